// Round 7
// baseline (25.974 us; speedup 1.0000x reference)
//
#include <hip/hip_runtime.h>

// Fixed problem shapes
#define N_PTS 2048
#define D_DIM 64
#define N_J   20
#define KD    192    // k-permuted features: [0:64) pred | [64:124) joints0-9 | [124:128) 0
                     //                      [128:188) joints10-19 | [188:192) 0
#define KDW   96     // dwords per Gb row
#define LDSW  200    // LDS row stride (bf16): 400 B = 25 x 16B slots (odd -> conflict-free)
#define T_TILES 32
#define NTILES 528
#define NUM_PAIRS_D 2098175.0

typedef __attribute__((ext_vector_type(8))) short bf16x8;   // MFMA A/B frag
typedef __attribute__((ext_vector_type(4))) float f32x4;    // MFMA C/D frag

// round-to-nearest-even f32 -> bf16 bits, packed pair
__device__ inline unsigned short f2bf(float f) {
    union { float f; unsigned int u; } v; v.f = f;
    unsigned int u = v.u;
    return (unsigned short)((u + 0x7FFFu + ((u >> 16) & 1u)) >> 16);
}
__device__ inline unsigned int pack2(float lo, float hi) {
    return (unsigned int)f2bf(lo) | ((unsigned int)f2bf(hi) << 16);
}

// ---------------------------------------------------------------------------
// Kernel 1: one-shot feature build. 4 rows per 256-thread block.
// Lanes 0-31 of each row-team: pred (2 elems each) + exact f32 sq-norm.
// Lanes 32-51: one joint each -> 6 bf16 lifted features (3 dwords).
// Lanes 52-53: zero pads.
// ---------------------------------------------------------------------------
__global__ __launch_bounds__(256)
void precompute_kernel(const float* __restrict__ pred,
                       const float* __restrict__ data,
                       unsigned int* __restrict__ Gb,   // [N][96] dwords
                       float* __restrict__ sq) {
    const int team = threadIdx.x >> 6;
    const int t    = threadIdx.x & 63;
    const int i    = blockIdx.x * 4 + team;
    unsigned int* __restrict__ grow = Gb + i * KDW;

    if (t < 32) {
        const float2 v = *(const float2*)&pred[i * D_DIM + 2 * t];
        grow[t] = pack2(v.x, v.y);
        float s = v.x * v.x + v.y * v.y;
        #pragma unroll
        for (int off = 16; off > 0; off >>= 1) s += __shfl_down(s, off, 32);
        if (t == 0) sq[i] = s;
    } else {
        const int jj = t - 32;
        if (jj < N_J) {
            float x = data[(i * N_J + jj) * 3 + 0];
            float y = data[(i * N_J + jj) * 3 + 1];
            float z = data[(i * N_J + jj) * 3 + 2];
            const float inv = rsqrtf(fmaxf(x * x + y * y + z * z, 1e-30f));
            x *= inv; y *= inv; z *= inv;
            const float s2 = 1.4142135623730951f;
            const int dw = (jj < 10) ? (32 + jj * 3) : (64 + (jj - 10) * 3);
            grow[dw + 0] = pack2(x * x, y * y);
            grow[dw + 1] = pack2(z * z, s2 * x * y);
            grow[dw + 2] = pack2(s2 * x * z, s2 * y * z);
        } else if (jj == 20) {
            grow[62] = 0u; grow[63] = 0u;    // pad k 124..127
        } else if (jj == 21) {
            grow[94] = 0u; grow[95] = 0u;    // pad k 188..191
        }
    }
}

// ---------------------------------------------------------------------------
// Kernel 2: one block per 64x64 upper-triangle pair tile. Staging is a pure
// coalesced copy of pre-built bf16 rows into padded LDS. 4 waves x 4 MFMA
// col-tiles, K=192 in 6 steps (2 -> accP, 4 -> accW). Epilogue computes
// |dist-dis|, block partial -> d_ws; the LAST block to finish (mod-trick
// atomic counter, works from any initial counter value) reduces all 528
// partials in f64 and writes the scalar. No memsets, no float atomics.
// ---------------------------------------------------------------------------
__global__ __launch_bounds__(256, 3)
void pairloss_kernel(const unsigned int* __restrict__ Gb,
                     const float* __restrict__ sq,
                     float* __restrict__ partials,
                     unsigned int* __restrict__ counter,
                     float* __restrict__ out) {
    __shared__ unsigned short Ash[64 * LDSW];
    __shared__ unsigned short Bsh[64 * LDSW];
    __shared__ float sqA[64], sqB[64], wsum[4];
    __shared__ bool  trig;
    __shared__ double dsh[4];

    // closed-form triangular tile decode (+safety fixup)
    const int t = blockIdx.x;
    int ib = (int)((65.0f - sqrtf(4225.0f - 8.0f * (float)t)) * 0.5f);
    if (ib > T_TILES - 1) ib = T_TILES - 1;
    if (ib < 0) ib = 0;
    #define TRI_OFF(i) ((i) * T_TILES - ((i) * ((i) - 1)) / 2)
    while (ib > 0 && t < TRI_OFF(ib)) --ib;
    while (ib < T_TILES - 1 && t >= TRI_OFF(ib + 1)) ++ib;
    const int jb = ib + (t - TRI_OFF(ib));

    const int tid = threadIdx.x;

    // ---- staging: pure copy, 12 x b128 per thread, coalesced + conflict-free
    // slot s in [0,3072): first 1536 = A tile (rows of ib), rest = B (rows of jb).
    // within tile: row r = s'/24, chunk c = s'%24; LDS slot = r*25 + c.
    {
        const uint4* __restrict__ g4 = (const uint4*)Gb;
        #pragma unroll
        for (int q = 0; q < 12; ++q) {
            const int s    = q * 256 + tid;
            const int sA   = (s < 1536) ? s : (s - 1536);
            const int r    = (int)(((unsigned)sA * 43691u) >> 20);   // sA / 24
            const int c    = sA - 24 * r;
            const int gr   = ((s < 1536) ? ib : jb) * 64 + r;
            const uint4 v  = g4[gr * 24 + c];
            unsigned short* __restrict__ sh = (s < 1536) ? Ash : Bsh;
            *(uint4*)&sh[(r * 25 + c) * 8] = v;
        }
    }
    if (tid < 64)        sqA[tid]      = sq[ib * 64 + tid];
    else if (tid < 128)  sqB[tid - 64] = sq[jb * 64 + (tid - 64)];
    __syncthreads();

    // ---- MFMA phase ----
    const int w  = tid >> 6;   // wave -> 16-row strip
    const int l  = tid & 63;
    const int lr = l & 15;     // frag row/col
    const int kg = l >> 4;     // k-group

    f32x4 accP[4], accW[4];
    #pragma unroll
    for (int c4 = 0; c4 < 4; ++c4) {
        accP[c4] = (f32x4){0.f, 0.f, 0.f, 0.f};
        accW[c4] = (f32x4){0.f, 0.f, 0.f, 0.f};
    }

    const unsigned short* Abase = &Ash[(w * 16 + lr) * LDSW + kg * 8];
    const unsigned short* Bbase = &Bsh[lr * LDSW + kg * 8];

    __builtin_amdgcn_s_setprio(1);
    #pragma unroll
    for (int ks = 0; ks < 6; ++ks) {
        const bf16x8 af = *(const bf16x8*)(Abase + ks * 32);
        #pragma unroll
        for (int c4 = 0; c4 < 4; ++c4) {
            const bf16x8 bf = *(const bf16x8*)(Bbase + c4 * 16 * LDSW + ks * 32);
            if (ks < 2)
                accP[c4] = __builtin_amdgcn_mfma_f32_16x16x32_bf16(af, bf, accP[c4], 0, 0, 0);
            else
                accW[c4] = __builtin_amdgcn_mfma_f32_16x16x32_bf16(af, bf, accW[c4], 0, 0, 0);
        }
    }
    __builtin_amdgcn_s_setprio(0);

    // ---- epilogue: D[row=(l>>4)*4+reg][col=l&15] ----
    const int ri0 = w * 16 + kg * 4;
    const int i0  = ib * 64 + ri0;
    float sqi[4];
    #pragma unroll
    for (int r = 0; r < 4; ++r) sqi[r] = sqA[ri0 + r];

    float local = 0.0f;
    #pragma unroll
    for (int c4 = 0; c4 < 4; ++c4) {
        const int jl = c4 * 16 + lr;
        const int j  = jb * 64 + jl;
        const float sqj = sqB[jl];
        #pragma unroll
        for (int r = 0; r < 4; ++r) {
            const int i = i0 + r;
            if (j > i) {
                const float d2   = fmaxf(sqi[r] + sqj - 2.0f * accP[c4][r], 0.0f);
                const float dist = sqrtf(d2);
                const float s    = fmaxf((float)N_J - accW[c4][r], 0.0f);
                local += fabsf(dist - sqrtf(s));
            }
        }
    }

    // wave reduce -> block partial
    #pragma unroll
    for (int off = 32; off > 0; off >>= 1) local += __shfl_down(local, off);
    if (l == 0) wsum[w] = local;
    __syncthreads();

    // last-arriver finalize (deterministic: fixed-order f64 sum of partials)
    if (tid == 0) {
        partials[blockIdx.x] = wsum[0] + wsum[1] + wsum[2] + wsum[3];
        __threadfence();                              // release, device scope
        const unsigned int old = atomicAdd(counter, 1u);
        trig = ((old % (unsigned)NTILES) == (unsigned)(NTILES - 1));
    }
    __syncthreads();
    if (trig) {
        __threadfence();                              // acquire, device scope
        double s = 0.0;
        for (int idx = tid; idx < NTILES; idx += 256)
            s += (double)((volatile const float*)partials)[idx];
        #pragma unroll
        for (int off = 32; off > 0; off >>= 1) s += __shfl_down(s, off);
        if ((tid & 63) == 0) dsh[tid >> 6] = s;
        __syncthreads();
        if (tid == 0)
            out[0] = (float)((dsh[0] + dsh[1] + dsh[2] + dsh[3]) / NUM_PAIRS_D);
    }
}

// ---------------------------------------------------------------------------
extern "C" void kernel_launch(void* const* d_in, const int* in_sizes, int n_in,
                              void* d_out, int out_size, void* d_ws, size_t ws_size,
                              hipStream_t stream) {
    const float* pred = (const float*)d_in[0];   // [2048, 64] f32
    const float* data = (const float*)d_in[1];   // [2048, 20, 3] f32
    float* out = (float*)d_out;

    char* ws = (char*)d_ws;
    unsigned int* Gb      = (unsigned int*)ws;                          // 2048*96*4 = 786432 B
    float*        sq      = (float*)(ws + 786432);                      // 8192 B
    float*        partials= (float*)(ws + 786432 + 8192);               // 528*4 B
    unsigned int* counter = (unsigned int*)(ws + 786432 + 8192 + 2112); // 4 B

    precompute_kernel<<<N_PTS / 4, 256, 0, stream>>>(pred, data, Gb, sq);
    pairloss_kernel<<<NTILES, 256, 0, stream>>>(Gb, sq, partials, counter, out);
}

// Round 8
// 19.253 us; speedup vs baseline: 1.3491x; 1.3491x over previous
//
#include <hip/hip_runtime.h>

// Fixed problem shapes
#define N_PTS 2048
#define D_DIM 64
#define N_J   20
#define LDSW  200    // LDS row stride (bf16): 400 B = 25 x 16B slots; odd slot count
                     // -> row-to-row bank-phase advances 1 mod 8: conflict-free b128
#define T_TILES 32   // 2048/64
#define NTILES 528   // T*(T+1)/2 upper-triangle 64x64 tiles
#define NUM_PAIRS_D 2098175.0   // N*(N+1)/2 - 1 (reference normalizer)

typedef __attribute__((ext_vector_type(8))) short bf16x8;   // MFMA A/B frag
typedef __attribute__((ext_vector_type(4))) float f32x4;    // MFMA C/D frag

// round-to-nearest-even f32 -> bf16 bits
__device__ inline unsigned short f2bf(float f) {
    union { float f; unsigned int u; } v; v.f = f;
    unsigned int u = v.u;
    return (unsigned short)((u + 0x7FFFu + ((u >> 16) & 1u)) >> 16);
}
__device__ inline unsigned int pack2(float lo, float hi) {
    return (unsigned int)f2bf(lo) | ((unsigned int)f2bf(hi) << 16);
}

// ---------------------------------------------------------------------------
// Single kernel: one block per 64x64 upper-triangle pair tile.
// Staging builds bf16 feature rows in LDS directly from pred/data
// (k-permuted: [0:64) pred | [64:124) joints0-9 | 4 zeros | [128:188)
// joints10-19 | 4 zeros). 4 waves x 4 MFMA col-tiles, K=192 in 6 steps
// (2 -> accP, 4 -> accW). Epilogue: |dist-dis| per strict-upper pair,
// wave+block reduce. Cross-block handoff is ATOMICS-ONLY (no __threadfence,
// no cache invalidates): atomicExch partial (return consumed = completion
// barrier), atomicAdd counter; the 528th incrementer (mod-trick: works from
// any poisoned initial value) reads partials via atomicOr(p,0) and does a
// fixed-order f64 sum -> deterministic scalar.
// ---------------------------------------------------------------------------
__global__ __launch_bounds__(256, 3)
void pairloss_kernel(const float* __restrict__ pred,
                     const float* __restrict__ data,
                     unsigned int* __restrict__ partials,   // 528 f32-as-u32
                     unsigned int* __restrict__ counter,
                     float* __restrict__ out) {
    __shared__ unsigned short Ash[64 * LDSW];
    __shared__ unsigned short Bsh[64 * LDSW];
    __shared__ float sqA[64], sqB[64], wsum[4];
    __shared__ bool  trig;
    __shared__ double dsh[4];

    // closed-form triangular tile decode (+safety fixup)
    const int t = blockIdx.x;
    int ib = (int)((65.0f - sqrtf(4225.0f - 8.0f * (float)t)) * 0.5f);
    if (ib > T_TILES - 1) ib = T_TILES - 1;
    if (ib < 0) ib = 0;
    #define TRI_OFF(i) ((i) * T_TILES - ((i) * ((i) - 1)) / 2)
    while (ib > 0 && t < TRI_OFF(ib)) --ib;
    while (ib < T_TILES - 1 && t >= TRI_OFF(ib + 1)) ++ib;
    const int jb = ib + (t - TRI_OFF(ib));

    const int tid = threadIdx.x;

    // ---- staging: threads 0..127 build A (rows of ib), 128..255 build B ----
    {
        const int half = tid >> 7;          // 0 = A, 1 = B
        const int r    = (tid >> 1) & 63;   // row within tile
        const int h    = tid & 1;           // half-row worker
        const int grow = (half ? jb : ib) * 64 + r;
        unsigned short* __restrict__ sh = half ? Bsh : Ash;

        // pred part: 32 f32 -> 4 x b128 bf16 stores (+ exact f32 sq-norm)
        const float4* __restrict__ p4 = (const float4*)&pred[grow * D_DIM + h * 32];
        float s = 0.f;
        #pragma unroll
        for (int q = 0; q < 4; ++q) {
            const float4 v0 = p4[2 * q];
            const float4 v1 = p4[2 * q + 1];
            s += v0.x * v0.x + v0.y * v0.y + v0.z * v0.z + v0.w * v0.w
               + v1.x * v1.x + v1.y * v1.y + v1.z * v1.z + v1.w * v1.w;
            uint4 u;
            u.x = pack2(v0.x, v0.y);
            u.y = pack2(v0.z, v0.w);
            u.z = pack2(v1.x, v1.y);
            u.w = pack2(v1.z, v1.w);
            *(uint4*)&sh[r * LDSW + h * 32 + q * 8] = u;
        }
        s += __shfl_xor(s, 1);
        if (h == 0) (half ? sqB : sqA)[r] = s;

        // joint part: 10 joints -> 30 bf16x2 dwords + 2 zero dwords = 8 x b128
        const float2* __restrict__ d2 = (const float2*)&data[grow * (N_J * 3) + h * 30];
        float buf[30];
        #pragma unroll
        for (int q = 0; q < 15; ++q) {
            const float2 v = d2[q];
            buf[2 * q] = v.x; buf[2 * q + 1] = v.y;
        }
        unsigned int wreg[32];
        const float s2 = 1.4142135623730951f;
        #pragma unroll
        for (int jj = 0; jj < 10; ++jj) {
            float x = buf[3 * jj], y = buf[3 * jj + 1], z = buf[3 * jj + 2];
            const float inv = rsqrtf(fmaxf(x * x + y * y + z * z, 1e-30f));
            x *= inv; y *= inv; z *= inv;
            wreg[3 * jj + 0] = pack2(x * x, y * y);
            wreg[3 * jj + 1] = pack2(z * z, s2 * x * y);
            wreg[3 * jj + 2] = pack2(s2 * x * z, s2 * y * z);
        }
        wreg[30] = 0u; wreg[31] = 0u;
        #pragma unroll
        for (int q = 0; q < 8; ++q) {
            uint4 u;
            u.x = wreg[4 * q + 0]; u.y = wreg[4 * q + 1];
            u.z = wreg[4 * q + 2]; u.w = wreg[4 * q + 3];
            *(uint4*)&sh[r * LDSW + D_DIM + h * 64 + q * 8] = u;
        }
    }
    __syncthreads();

    // ---- MFMA phase ----
    const int w  = tid >> 6;   // wave -> 16-row strip
    const int l  = tid & 63;
    const int lr = l & 15;     // frag row/col
    const int kg = l >> 4;     // k-group

    f32x4 accP[4], accW[4];
    #pragma unroll
    for (int c4 = 0; c4 < 4; ++c4) {
        accP[c4] = (f32x4){0.f, 0.f, 0.f, 0.f};
        accW[c4] = (f32x4){0.f, 0.f, 0.f, 0.f};
    }

    const unsigned short* Abase = &Ash[(w * 16 + lr) * LDSW + kg * 8];
    const unsigned short* Bbase = &Bsh[lr * LDSW + kg * 8];

    __builtin_amdgcn_s_setprio(1);
    #pragma unroll
    for (int ks = 0; ks < 6; ++ks) {
        const bf16x8 af = *(const bf16x8*)(Abase + ks * 32);
        #pragma unroll
        for (int c4 = 0; c4 < 4; ++c4) {
            const bf16x8 bf = *(const bf16x8*)(Bbase + c4 * 16 * LDSW + ks * 32);
            if (ks < 2)
                accP[c4] = __builtin_amdgcn_mfma_f32_16x16x32_bf16(af, bf, accP[c4], 0, 0, 0);
            else
                accW[c4] = __builtin_amdgcn_mfma_f32_16x16x32_bf16(af, bf, accW[c4], 0, 0, 0);
        }
    }
    __builtin_amdgcn_s_setprio(0);

    // ---- epilogue: D[row=(l>>4)*4+reg][col=l&15] ----
    const int ri0 = w * 16 + kg * 4;
    const int i0  = ib * 64 + ri0;
    float sqi[4];
    #pragma unroll
    for (int r = 0; r < 4; ++r) sqi[r] = sqA[ri0 + r];

    float local = 0.0f;
    #pragma unroll
    for (int c4 = 0; c4 < 4; ++c4) {
        const int jl = c4 * 16 + lr;
        const int j  = jb * 64 + jl;
        const float sqj = sqB[jl];
        #pragma unroll
        for (int r = 0; r < 4; ++r) {
            const int i = i0 + r;
            if (j > i) {
                const float d2   = fmaxf(sqi[r] + sqj - 2.0f * accP[c4][r], 0.0f);
                const float dist = sqrtf(d2);
                const float s    = fmaxf((float)N_J - accW[c4][r], 0.0f);
                local += fabsf(dist - sqrtf(s));
            }
        }
    }

    // wave reduce -> block partial
    #pragma unroll
    for (int off = 32; off > 0; off >>= 1) local += __shfl_down(local, off);
    if (l == 0) wsum[w] = local;
    __syncthreads();

    // ---- atomics-only last-arriver finalize ----
    if (tid == 0) {
        const float bp = wsum[0] + wsum[1] + wsum[2] + wsum[3];
        // device-scope coherent write of this block's partial; consuming the
        // return value forces completion before the counter increment issues.
        unsigned int old = atomicExch(&partials[blockIdx.x], __float_as_uint(bp));
        asm volatile("" :: "v"(old));   // keep the dependency live
        const unsigned int c = atomicAdd(counter, 1u);
        trig = ((c % (unsigned)NTILES) == (unsigned)(NTILES - 1));
    }
    __syncthreads();

    if (trig) {
        // atomic loads from the coherent point (never stale L1/L2), fixed order
        double s = 0.0;
        for (int idx = tid; idx < NTILES; idx += 256)
            s += (double)__uint_as_float(atomicOr(&partials[idx], 0u));
        #pragma unroll
        for (int off = 32; off > 0; off >>= 1) s += __shfl_down(s, off);
        if ((tid & 63) == 0) dsh[tid >> 6] = s;
        __syncthreads();
        if (tid == 0)
            out[0] = (float)((dsh[0] + dsh[1] + dsh[2] + dsh[3]) / NUM_PAIRS_D);
    }
}

// ---------------------------------------------------------------------------
extern "C" void kernel_launch(void* const* d_in, const int* in_sizes, int n_in,
                              void* d_out, int out_size, void* d_ws, size_t ws_size,
                              hipStream_t stream) {
    const float* pred = (const float*)d_in[0];   // [2048, 64] f32
    const float* data = (const float*)d_in[1];   // [2048, 20, 3] f32
    float* out = (float*)d_out;

    unsigned int* partials = (unsigned int*)d_ws;                 // 528 u32
    unsigned int* counter  = (unsigned int*)((char*)d_ws + 2112); // 1 u32

    pairloss_kernel<<<NTILES, 256, 0, stream>>>(pred, data, partials, counter, out);
}

// Round 9
// 18.437 us; speedup vs baseline: 1.4088x; 1.0443x over previous
//
#include <hip/hip_runtime.h>

// Fixed problem shapes
#define N_PTS 2048
#define D_DIM 64
#define N_J   20
#define KD    192    // 64 pred + 2x(60 features + 4 zero pad)
#define LDSW  200    // LDS row stride (bf16): 400 B = 25 x 16B slots; odd slot count
                     // -> row-to-row bank-phase advances 1 mod 8: conflict-free b128
#define T_TILES 32   // 2048/64
#define NTILES 528   // T*(T+1)/2 upper-triangle 64x64 tiles
#define NUM_PAIRS_D 2098175.0   // N*(N+1)/2 - 1 (reference normalizer)

typedef __attribute__((ext_vector_type(8))) short bf16x8;   // MFMA A/B frag
typedef __attribute__((ext_vector_type(4))) float f32x4;    // MFMA C/D frag

// round-to-nearest-even f32 -> bf16 bits
__device__ inline unsigned short f2bf(float f) {
    union { float f; unsigned int u; } v; v.f = f;
    unsigned int u = v.u;
    return (unsigned short)((u + 0x7FFFu + ((u >> 16) & 1u)) >> 16);
}
__device__ inline unsigned int pack2(float lo, float hi) {
    return (unsigned int)f2bf(lo) | ((unsigned int)f2bf(hi) << 16);
}

// ---------------------------------------------------------------------------
// One block per 64x64 upper-triangle pair tile. Feature columns use a fixed
// k-permutation (dot-invariant): k[0:64) = pred, k[64:128) = joints 0-9
// lifted features (60) + 4 zeros, k[128:192) = joints 10-19 (60) + 4 zeros.
// Each half-row worker owns a contiguous 128 B span -> all-b128 staging.
// 4 waves x 4 MFMA col-tiles, K=192 in 6 steps (2 -> accP, 4 -> accW).
// Epilogue: |dist-dis| per strict-upper pair, wave reduce, one store/block.
// NOTE (R7/R8 lessons): no in-graph memsets (39us/dispatch), no
// __threadfence (L2-invalidating), no cross-block finalize fusion (racy AND
// slower). Two plain dispatches is the proven optimum.
// ---------------------------------------------------------------------------
__global__ __launch_bounds__(256, 3)
void pairloss_kernel(const float* __restrict__ pred,
                     const float* __restrict__ data,
                     float* __restrict__ partials) {
    __shared__ unsigned short Ash[64 * LDSW];
    __shared__ unsigned short Bsh[64 * LDSW];
    __shared__ float sqA[64], sqB[64], wsum[4];

    // closed-form triangular tile decode (+safety fixup)
    const int t = blockIdx.x;
    int ib = (int)((65.0f - sqrtf(4225.0f - 8.0f * (float)t)) * 0.5f);
    if (ib > T_TILES - 1) ib = T_TILES - 1;
    if (ib < 0) ib = 0;
    #define TRI_OFF(i) ((i) * T_TILES - ((i) * ((i) - 1)) / 2)
    while (ib > 0 && t < TRI_OFF(ib)) --ib;
    while (ib < T_TILES - 1 && t >= TRI_OFF(ib + 1)) ++ib;
    const int jb = ib + (t - TRI_OFF(ib));

    const int tid = threadIdx.x;

    // ---- staging: threads 0..127 build A (rows of ib), 128..255 build B ----
    {
        const int half = tid >> 7;          // 0 = A, 1 = B
        const int r    = (tid >> 1) & 63;   // row within tile
        const int h    = tid & 1;           // half-row worker
        const int grow = (half ? jb : ib) * 64 + r;
        unsigned short* __restrict__ sh = half ? Bsh : Ash;

        // pred part: 32 f32 -> 4 x b128 bf16 stores (+ exact f32 sq-norm)
        const float4* __restrict__ p4 = (const float4*)&pred[grow * D_DIM + h * 32];
        float s = 0.f;
        #pragma unroll
        for (int q = 0; q < 4; ++q) {
            const float4 v0 = p4[2 * q];
            const float4 v1 = p4[2 * q + 1];
            s += v0.x * v0.x + v0.y * v0.y + v0.z * v0.z + v0.w * v0.w
               + v1.x * v1.x + v1.y * v1.y + v1.z * v1.z + v1.w * v1.w;
            uint4 u;
            u.x = pack2(v0.x, v0.y);
            u.y = pack2(v0.z, v0.w);
            u.z = pack2(v1.x, v1.y);
            u.w = pack2(v1.z, v1.w);
            *(uint4*)&sh[r * LDSW + h * 32 + q * 8] = u;
        }
        s += __shfl_xor(s, 1);
        if (h == 0) (half ? sqB : sqA)[r] = s;

        // joint part: 10 joints -> 30 bf16x2 dwords + 2 zero dwords = 8 x b128
        const float2* __restrict__ d2 = (const float2*)&data[grow * (N_J * 3) + h * 30];
        float buf[30];
        #pragma unroll
        for (int q = 0; q < 15; ++q) {
            const float2 v = d2[q];
            buf[2 * q] = v.x; buf[2 * q + 1] = v.y;
        }
        unsigned int wreg[32];
        const float s2 = 1.4142135623730951f;
        #pragma unroll
        for (int jj = 0; jj < 10; ++jj) {
            float x = buf[3 * jj], y = buf[3 * jj + 1], z = buf[3 * jj + 2];
            const float inv = rsqrtf(fmaxf(x * x + y * y + z * z, 1e-30f));
            x *= inv; y *= inv; z *= inv;
            wreg[3 * jj + 0] = pack2(x * x, y * y);
            wreg[3 * jj + 1] = pack2(z * z, s2 * x * y);
            wreg[3 * jj + 2] = pack2(s2 * x * z, s2 * y * z);
        }
        wreg[30] = 0u; wreg[31] = 0u;
        #pragma unroll
        for (int q = 0; q < 8; ++q) {
            uint4 u;
            u.x = wreg[4 * q + 0]; u.y = wreg[4 * q + 1];
            u.z = wreg[4 * q + 2]; u.w = wreg[4 * q + 3];
            *(uint4*)&sh[r * LDSW + D_DIM + h * 64 + q * 8] = u;
        }
    }
    __syncthreads();

    // ---- MFMA phase ----
    const int w  = tid >> 6;   // wave -> 16-row strip
    const int l  = tid & 63;
    const int lr = l & 15;     // frag row/col
    const int kg = l >> 4;     // k-group

    f32x4 accP[4], accW[4];
    #pragma unroll
    for (int c4 = 0; c4 < 4; ++c4) {
        accP[c4] = (f32x4){0.f, 0.f, 0.f, 0.f};
        accW[c4] = (f32x4){0.f, 0.f, 0.f, 0.f};
    }

    const unsigned short* Abase = &Ash[(w * 16 + lr) * LDSW + kg * 8];
    const unsigned short* Bbase = &Bsh[lr * LDSW + kg * 8];

    __builtin_amdgcn_s_setprio(1);
    #pragma unroll
    for (int ks = 0; ks < 6; ++ks) {
        const bf16x8 af = *(const bf16x8*)(Abase + ks * 32);
        #pragma unroll
        for (int c4 = 0; c4 < 4; ++c4) {
            const bf16x8 bf = *(const bf16x8*)(Bbase + c4 * 16 * LDSW + ks * 32);
            if (ks < 2)
                accP[c4] = __builtin_amdgcn_mfma_f32_16x16x32_bf16(af, bf, accP[c4], 0, 0, 0);
            else
                accW[c4] = __builtin_amdgcn_mfma_f32_16x16x32_bf16(af, bf, accW[c4], 0, 0, 0);
        }
    }
    __builtin_amdgcn_s_setprio(0);

    // ---- epilogue: D[row=(l>>4)*4+reg][col=l&15] ----
    const int ri0 = w * 16 + kg * 4;
    const int i0  = ib * 64 + ri0;
    float sqi[4];
    #pragma unroll
    for (int r = 0; r < 4; ++r) sqi[r] = sqA[ri0 + r];

    float local = 0.0f;
    #pragma unroll
    for (int c4 = 0; c4 < 4; ++c4) {
        const int jl = c4 * 16 + lr;
        const int j  = jb * 64 + jl;
        const float sqj = sqB[jl];
        #pragma unroll
        for (int r = 0; r < 4; ++r) {
            const int i = i0 + r;
            if (j > i) {
                const float d2   = fmaxf(sqi[r] + sqj - 2.0f * accP[c4][r], 0.0f);
                const float dist = sqrtf(d2);
                const float s    = fmaxf((float)N_J - accW[c4][r], 0.0f);
                local += fabsf(dist - sqrtf(s));
            }
        }
    }

    // wave reduce -> block partial (deterministic, no atomics)
    #pragma unroll
    for (int off = 32; off > 0; off >>= 1) local += __shfl_down(local, off);
    if (l == 0) wsum[w] = local;
    __syncthreads();
    if (tid == 0) partials[blockIdx.x] = wsum[0] + wsum[1] + wsum[2] + wsum[3];
}

// ---------------------------------------------------------------------------
// Finalize: deterministic f64 sum of 528 partials (fixed lane->index map).
// ---------------------------------------------------------------------------
__global__ __launch_bounds__(256)
void finalize_kernel(const float* __restrict__ partials, float* __restrict__ out) {
    double s = 0.0;
    for (int i = threadIdx.x; i < NTILES; i += 256) s += (double)partials[i];
    #pragma unroll
    for (int off = 32; off > 0; off >>= 1) s += __shfl_down(s, off);
    __shared__ double sh4[4];
    if ((threadIdx.x & 63) == 0) sh4[threadIdx.x >> 6] = s;
    __syncthreads();
    if (threadIdx.x == 0)
        out[0] = (float)((sh4[0] + sh4[1] + sh4[2] + sh4[3]) / NUM_PAIRS_D);
}

// ---------------------------------------------------------------------------
extern "C" void kernel_launch(void* const* d_in, const int* in_sizes, int n_in,
                              void* d_out, int out_size, void* d_ws, size_t ws_size,
                              hipStream_t stream) {
    const float* pred = (const float*)d_in[0];   // [2048, 64] f32
    const float* data = (const float*)d_in[1];   // [2048, 20, 3] f32
    float* out = (float*)d_out;

    float* partials = (float*)d_ws;              // 528 f32

    pairloss_kernel<<<NTILES, 256, 0, stream>>>(pred, data, partials);
    finalize_kernel<<<1, 256, 0, stream>>>(partials, out);
}